// Round 7
// baseline (388.555 us; speedup 1.0000x reference)
//
#include <hip/hip_runtime.h>
#include <hip/hip_bf16.h>

// ============================================================================
// HRR "self-attention" on MI355X (gfx950).
//
// Math: q,k,v = x @ W{q,k,v}^T ; all HRR ops are frequency-domain:
//   out = irfft( cumsum_S( (Fk/(|Fk|+eps)) * Fv ) * conj(Fq/(|Fq|+eps)) )
// (the reference's irfft->rfft round-trips are identities on the Hermitian
//  half-spectrum — bins 0 and 512 stay exactly real; cumsum over S commutes
//  with rfft over D).
//
// Pipeline:
//  0. tw_init_k           : 768-entry twiddle table -> global (6 KB, once).
//  1. prep_x_k / prep_w_k : f32 -> bf16 hi/lo split (Ozaki 3-product GEMM,
//                           ~2^-17 relative error, f32-grade).
//  2. gemm_split_k        : C[8192x3072] = A'[8192x3072] . B'[3072x3072]^T,
//                           A' = (x_hi|x_hi|x_lo), B' = (W_hi|W_lo|W_hi),
//                           W = (Wq;Wk;Wv). m97-style 128x128x32 MFMA tile.
//  3. fwd_fft_k           : per (b,s) row: 1024-pt complex RADIX-4 FFT of
//                           (k + i*v) gives Fk,Fv; second FFT gives Fq.
//                           Writes Fkv [B][513][S] (bin-major, for the scan)
//                           and Fqh IN-PLACE over the row's own qkv storage.
//  4. scan_s_k            : inclusive cumsum along S per (b,bin) chain.
//  5. inv_fft_k           : P = Fkv_cum * conj(Fqh); Hermitian-extend;
//                           irfft via Re(FFT(conj(Y)))/N; write f32 out.
//
// FFT: radix-4 DIT (5 stages, base-4 digit-reversed input, natural output).
// LDS array is padded via ZIDX(e)=e+(e>>4): without it, stride-L butterflies
// collide 16-way on the 32-bank LDS (elements e==e' mod 16 share a bank
// pair); with it, per-instruction lane bases spread over all bank pairs
// (collision would need 256-elem separation). Stage-0 quads never cross a
// 16-boundary, so contiguous vector reads survive the remap.
// Twiddles come from the precomputed global table (L1/L2-resident) instead
// of 768 sincosf per block (~150 serial VALU instrs/thread of preamble).
//
// Workspace (142 MiB peak, aliased):
//   [0,32M)    xhi|xlo  (dead after GEMM)  === fkv (first written in fwd_fft)
//   [33M,+6KB) gtw (twiddle table, persists whole launch)
//   [34,46M)   whi|wlo  (dead after GEMM)
//   [46,142M)  qkv f32  (rows also carry Fqh in-place after fwd_fft)
// ============================================================================

using bf16 = __hip_bfloat16;

typedef __attribute__((ext_vector_type(8))) short bf16x8;
typedef __attribute__((ext_vector_type(4))) float f32x4;

#define DEV static __device__ __forceinline__

#define BB 4
#define SS 2048
#define DD 1024
#define BS (BB * SS)   // 8192 rows
#define NBIN 513
#define N3 3072

// Padded LDS index: bijective, strictly increasing, max 1086 (< 1088).
#define ZIDX(e) ((e) + ((e) >> 4))
#define ZLEN 1088

DEV float2 cmul(float2 a, float2 b) { return make_float2(a.x*b.x - a.y*b.y, a.x*b.y + a.y*b.x); }
DEV float2 cadd(float2 a, float2 b) { return make_float2(a.x + b.x, a.y + b.y); }
DEV float2 csub(float2 a, float2 b) { return make_float2(a.x - b.x, a.y - b.y); }
DEV float2 conjf2(float2 a) { return make_float2(a.x, -a.y); }

// Reverse the 5 base-4 digits of a 10-bit index (involution).
DEV int rev4(int n) {
  int r = 0;
#pragma unroll
  for (int d = 0; d < 5; ++d) { r = (r << 2) | (n & 3); n >>= 2; }
  return r;
}

DEV void bf16_split(float v, ushort &hi, ushort &lo) {
  bf16 hb = __float2bfloat16(v);
  float hf = __bfloat162float(hb);
  bf16 lb = __float2bfloat16(v - hf);
  hi = *reinterpret_cast<ushort*>(&hb);
  lo = *reinterpret_cast<ushort*>(&lb);
}

// ---------------------------------------------------------------------------
// gtw[i] = e^{-2pi*I*i/1024}, i in [0,768): max radix-4 exponent is 3*255=765.
__global__ __launch_bounds__(256) void tw_init_k(float2* __restrict__ gtw) {
  const int i = blockIdx.x * 256 + threadIdx.x;      // grid=3 -> i in [0,768)
  float sv, cv;
  sincosf(-6.283185307179586f * (float)i * (1.0f / 1024.0f), &sv, &cv);
  gtw[i] = make_float2(cv, sv);
}

// Copy global twiddle table into this block's LDS (3 coalesced loads/thread).
DEV void init_tw(float2* tw, const float2* __restrict__ gtw, const int tid) {
#pragma unroll
  for (int rep = 0; rep < 3; ++rep) {
    const int i = tid + rep * 256;
    tw[i] = gtw[i];
  }
}

// ---------------------------------------------------------------------------
__global__ __launch_bounds__(256) void prep_x_k(const float* __restrict__ x,
                                                bf16* __restrict__ xhi,
                                                bf16* __restrict__ xlo) {
  const int i = blockIdx.x * 256 + threadIdx.x;      // float4 index
  const float4 v = reinterpret_cast<const float4*>(x)[i];
  const float f[4] = {v.x, v.y, v.z, v.w};
  ushort h[4], l[4];
#pragma unroll
  for (int j = 0; j < 4; ++j) bf16_split(f[j], h[j], l[j]);
  reinterpret_cast<ushort4*>(xhi)[i] = make_ushort4(h[0], h[1], h[2], h[3]);
  reinterpret_cast<ushort4*>(xlo)[i] = make_ushort4(l[0], l[1], l[2], l[3]);
}

__global__ __launch_bounds__(256) void prep_w_k(const float* __restrict__ wq,
                                                const float* __restrict__ wk,
                                                const float* __restrict__ wv,
                                                bf16* __restrict__ whi,
                                                bf16* __restrict__ wlo) {
  const int i = blockIdx.x * 256 + threadIdx.x;      // float4 index
  const int e = i << 2;
  const int row = e >> 10;                           // 0..3071 over (Wq;Wk;Wv)
  const float* src = (row < 1024) ? wq : ((row < 2048) ? wk : wv);
  const float4 v = *reinterpret_cast<const float4*>(src + (size_t)(row & 1023) * 1024 + (e & 1023));
  const float f[4] = {v.x, v.y, v.z, v.w};
  ushort h[4], l[4];
#pragma unroll
  for (int j = 0; j < 4; ++j) bf16_split(f[j], h[j], l[j]);
  reinterpret_cast<ushort4*>(whi)[i] = make_ushort4(h[0], h[1], h[2], h[3]);
  reinterpret_cast<ushort4*>(wlo)[i] = make_ushort4(l[0], l[1], l[2], l[3]);
}

// ---------------------------------------------------------------------------
DEV void load_lds16(const bf16* g, bf16* l) {
  __builtin_amdgcn_global_load_lds((const __attribute__((address_space(1))) void*)g,
                                   (__attribute__((address_space(3))) void*)l, 16, 0, 0);
}

// C = A'.B'^T, M=8192, N=3072, K'=3072. 128x128 tile, BK=32, 4 waves (2x2).
__global__ __launch_bounds__(256, 2) void gemm_split_k(const bf16* __restrict__ xhi,
                                                       const bf16* __restrict__ xlo,
                                                       const bf16* __restrict__ whi,
                                                       const bf16* __restrict__ wlo,
                                                       float* __restrict__ qkv) {
  __shared__ bf16 At[128 * 32];
  __shared__ bf16 Bt[128 * 32];
  const int tid = threadIdx.x;
  const int lane = tid & 63;
  const int w = tid >> 6;
  const int wr = w >> 1, wc = w & 1;
  // XCD-chunked swizzle: 1536 blocks (1536%8==0 -> bijective); consecutive
  // logical blocks (same A-panel, bm = logical/24) stay on one XCD's L2. [T1]
  const int bid = blockIdx.x;
  const int logical = (bid & 7) * (1536 / 8) + (bid >> 3);
  const int bn = logical % (N3 / 128);
  const int bm = logical / (N3 / 128);
  const int rowBase = bm * 128;
  const int colBase = bn * 128;

  // staging: 8 chunks of 1KB per tile; wave w issues chunks 2w, 2w+1.
  // gload_lds writes lane l at LDS elem chunkBase + 8l; our [row][k] tile
  // mapping row=c*16+l/4, kcol=(l&3)*8 linearizes to (l/4)*32+(l%4)*8 = 8l,
  // matching the per-lane global source below.
  const int c0 = w * 2, c1 = c0 + 1;
  const int srow0 = c0 * 16 + (lane >> 2);
  const int srow1 = c1 * 16 + (lane >> 2);
  const int skoff = (lane & 3) * 8;

  // MFMA fragment coords (16x16x32): row/col = lane&15, k = (lane>>4)*8
  const int lr = lane & 15;
  const int lk = (lane >> 4) * 8;

  f32x4 acc[4][4];
#pragma unroll
  for (int m = 0; m < 4; ++m)
#pragma unroll
    for (int n = 0; n < 4; ++n) acc[m][n] = 0.0f;

  for (int ks = 0; ks < 96; ++ks) {
    const int k0 = ks * 32;
    const int part = k0 >> 10;                 // 0: hi.hi  1: hi.lo  2: lo.hi
    const int kb = (k0 & 1023) + skoff;
    const bf16* As = (part < 2) ? xhi : xlo;
    const bf16* Bs = (part == 1) ? wlo : whi;
    __syncthreads();
    load_lds16(As + (size_t)(rowBase + srow0) * 1024 + kb, &At[c0 * 512]);
    load_lds16(As + (size_t)(rowBase + srow1) * 1024 + kb, &At[c1 * 512]);
    load_lds16(Bs + (size_t)(colBase + srow0) * 1024 + kb, &Bt[c0 * 512]);
    load_lds16(Bs + (size_t)(colBase + srow1) * 1024 + kb, &Bt[c1 * 512]);
    __syncthreads();   // compiler drains vmcnt here => tiles ready
    bf16x8 af[4], bfr[4];
#pragma unroll
    for (int m = 0; m < 4; ++m)
      af[m] = *reinterpret_cast<const bf16x8*>(&At[(wr * 64 + m * 16 + lr) * 32 + lk]);
#pragma unroll
    for (int n = 0; n < 4; ++n)
      bfr[n] = *reinterpret_cast<const bf16x8*>(&Bt[(wc * 64 + n * 16 + lr) * 32 + lk]);
#pragma unroll
    for (int m = 0; m < 4; ++m)
#pragma unroll
      for (int n = 0; n < 4; ++n)
        acc[m][n] = __builtin_amdgcn_mfma_f32_16x16x32_bf16(af[m], bfr[n], acc[m][n], 0, 0, 0);
  }

  // C/D layout (m89-verified): col = lane&15, row = (lane>>4)*4 + reg
  const int ocol = colBase + wc * 64 + (lane & 15);
  const int orow = rowBase + wr * 64 + (lane >> 4) * 4;
#pragma unroll
  for (int m = 0; m < 4; ++m)
#pragma unroll
    for (int n = 0; n < 4; ++n)
#pragma unroll
      for (int j = 0; j < 4; ++j)
        qkv[(size_t)(orow + m * 16 + j) * N3 + ocol + n * 16] = acc[m][n][j];
}

// ---------------------------------------------------------------------------
// In-LDS 1024-pt complex radix-4 DIT FFT over the ZIDX-padded array.
// Input base-4 digit-reversed, output natural order. 5 stages; 256 threads
// x 1 radix-4 butterfly/stage. Stage s (L=4^s): t_r = W^(r*i*256/L) *
// Z[base+rL], y_k = sum_r (-i)^{kr} t_r  (W = e^{-2pi*I/1024}).
DEV void fft1024_r4(float2* Z, const float2* tw, const int tid) {
#pragma unroll
  for (int s = 0; s < 5; ++s) {
    const int ls = 2 * s;
    const int L = 1 << ls;                     // 4^s
    const int i = tid & (L - 1);
    const int base = ((tid >> ls) << (ls + 2)) + i;   // g*4L + i
    const int tsh = 8 - ls;                    // twiddle step 256/L
    const float2 a = Z[ZIDX(base)];
    const float2 b = cmul(tw[i << tsh], Z[ZIDX(base + L)]);
    const float2 c = cmul(tw[(2 * i) << tsh], Z[ZIDX(base + 2 * L)]);
    const float2 d = cmul(tw[(3 * i) << tsh], Z[ZIDX(base + 3 * L)]);
    const float2 acp = cadd(a, c), acm = csub(a, c);
    const float2 bdp = cadd(b, d), bdm = csub(b, d);
    Z[ZIDX(base)]         = cadd(acp, bdp);                            // y0
    Z[ZIDX(base + L)]     = make_float2(acm.x + bdm.y, acm.y - bdm.x); // y1 = acm + (-i)bdm
    Z[ZIDX(base + 2 * L)] = csub(acp, bdp);                            // y2
    Z[ZIDX(base + 3 * L)] = make_float2(acm.x - bdm.y, acm.y + bdm.x); // y3 = acm + (i)bdm
    __syncthreads();
  }
}

__global__ __launch_bounds__(256) void fwd_fft_k(float* __restrict__ qkv,
                                                 float2* __restrict__ fkv,   // [B][513][S]
                                                 const float2* __restrict__ gtw) {
  __shared__ float2 Z[ZLEN];
  __shared__ float2 tw[768];
  const int tid = threadIdx.x;
  // XCD-chunked swizzle: consecutive s on one XCD so the 8 blocks sharing
  // each 64B fkv line merge their scattered 8B writes in that XCD's L2.
  const int bid = blockIdx.x;
  const int row = (bid & 7) * (BS / 8) + (bid >> 3);   // b*2048 + s
  const int b = row >> 11, s = row & 2047;
  init_tw(tw, gtw, tid);

  const float* kr = qkv + (size_t)row * N3 + DD;
  const float* vr = qkv + (size_t)row * N3 + 2 * DD;
  {
    const float4 k4 = reinterpret_cast<const float4*>(kr)[tid];
    const float4 v4 = reinterpret_cast<const float4*>(vr)[tid];
    const float kk[4] = {k4.x, k4.y, k4.z, k4.w};
    const float vv[4] = {v4.x, v4.y, v4.z, v4.w};
#pragma unroll
    for (int j = 0; j < 4; ++j) Z[ZIDX(rev4(tid * 4 + j))] = make_float2(kk[j], vv[j]);
  }
  __syncthreads();   // covers tw LDS-copy + Z scatter
  fft1024_r4(Z, tw, tid);
  // Z = FFT(k + i v): Fk = (Z[j]+conj(Z[N-j]))/2, Fv = -i(Z[j]-conj(Z[N-j]))/2
  for (int j = tid; j <= 512; j += 256) {
    const float2 Zj = Z[ZIDX(j)];
    const float2 Zc = conjf2(Z[ZIDX((1024 - j) & 1023)]);
    const float2 Fk = make_float2(0.5f * (Zj.x + Zc.x), 0.5f * (Zj.y + Zc.y));
    const float2 dv = csub(Zj, Zc);
    const float2 Fv = make_float2(0.5f * dv.y, -0.5f * dv.x);
    const float inv = 1.0f / (sqrtf(Fk.x * Fk.x + Fk.y * Fk.y) + 1e-8f);
    const float2 Fkh = make_float2(Fk.x * inv, Fk.y * inv);
    fkv[((size_t)b * NBIN + j) * SS + s] = cmul(Fkh, Fv);
  }
  __syncthreads();   // all reads of Z done before reuse

  // --- q FFT; Fqh written IN-PLACE over this row's own qkv storage. ---
  // Safe: the fqh values depend (through LDS Z + fft barriers) on the
  // q-reads, so no write can precede its read. fqh_row[512] spills 2 floats
  // into the row's k-section (floats 1024-1025) — also safe: this block is
  // the only toucher of the row and its k-read happened above.
  const float* qr = qkv + (size_t)row * N3;
  {
    const float4 q4 = reinterpret_cast<const float4*>(qr)[tid];
    const float qq[4] = {q4.x, q4.y, q4.z, q4.w};
#pragma unroll
    for (int j = 0; j < 4; ++j) Z[ZIDX(rev4(tid * 4 + j))] = make_float2(qq[j], 0.0f);
  }
  __syncthreads();
  fft1024_r4(Z, tw, tid);
  float2* fqh_row = reinterpret_cast<float2*>(qkv + (size_t)row * N3);
  for (int j = tid; j <= 512; j += 256) {
    const float2 Fq = Z[ZIDX(j)];
    const float inv = 1.0f / (sqrtf(Fq.x * Fq.x + Fq.y * Fq.y) + 1e-8f);
    fqh_row[j] = make_float2(Fq.x * inv, Fq.y * inv);
  }
}

// ---------------------------------------------------------------------------
// Inclusive cumsum over S=2048 complex values; one block per (b,bin) chain.
__global__ __launch_bounds__(256) void scan_s_k(float2* __restrict__ fkv) {
  __shared__ float2 sums[256];
  const int tid = threadIdx.x;
  float2* p = fkv + (size_t)blockIdx.x * SS;
  float4* p4 = reinterpret_cast<float4*>(p);
  float4 d[4];
#pragma unroll
  for (int i = 0; i < 4; ++i) d[i] = p4[tid * 4 + i];
  float2* e = reinterpret_cast<float2*>(d);
#pragma unroll
  for (int i = 1; i < 8; ++i) e[i] = cadd(e[i], e[i - 1]);
  const float2 mytot = e[7];
  sums[tid] = mytot;
  float2 run = mytot;
  __syncthreads();
  for (int off = 1; off < 256; off <<= 1) {
    float2 addv = make_float2(0.0f, 0.0f);
    if (tid >= off) addv = sums[tid - off];
    __syncthreads();
    run = cadd(run, addv);
    sums[tid] = run;
    __syncthreads();
  }
  const float2 pre = csub(run, mytot);        // exclusive prefix of thread totals
#pragma unroll
  for (int i = 0; i < 8; ++i) e[i] = cadd(e[i], pre);
#pragma unroll
  for (int i = 0; i < 4; ++i) p4[tid * 4 + i] = d[i];
}

// ---------------------------------------------------------------------------
__global__ __launch_bounds__(256) void inv_fft_k(const float2* __restrict__ fkv,
                                                 const float* __restrict__ qkv,
                                                 float* __restrict__ out,
                                                 const float2* __restrict__ gtw) {
  __shared__ float2 Z[ZLEN];
  __shared__ float2 tw[768];
  const int tid = threadIdx.x;
  const int bid = blockIdx.x;
  const int row = (bid & 7) * (BS / 8) + (bid >> 3);   // XCD-chunked swizzle
  const int b = row >> 11, s = row & 2047;
  init_tw(tw, gtw, tid);

  // Y[j]=P[j] (j<=512), Y[1024-j]=conj(P[j]). FFT(conj(Y)) then Re()/N.
  const float2* fqh_row = reinterpret_cast<const float2*>(qkv + (size_t)row * N3);
  for (int j = tid; j <= 512; j += 256) {
    const float2 kv = fkv[((size_t)b * NBIN + j) * SS + s];
    const float2 qh = fqh_row[j];
    const float2 P = cmul(kv, conjf2(qh));
    Z[ZIDX(rev4(j))] = conjf2(P);
    if (j > 0 && j < 512) Z[ZIDX(rev4(1024 - j))] = P;
  }
  __syncthreads();   // covers tw LDS-copy + Z scatter
  fft1024_r4(Z, tw, tid);
  const float sc = 1.0f / 1024.0f;
  float4* o4 = reinterpret_cast<float4*>(out + (size_t)row * DD);
  o4[tid] = make_float4(Z[ZIDX(tid * 4 + 0)].x * sc, Z[ZIDX(tid * 4 + 1)].x * sc,
                        Z[ZIDX(tid * 4 + 2)].x * sc, Z[ZIDX(tid * 4 + 3)].x * sc);
}

// ---------------------------------------------------------------------------
extern "C" void kernel_launch(void* const* d_in, const int* in_sizes, int n_in,
                              void* d_out, int out_size, void* d_ws, size_t ws_size,
                              hipStream_t stream) {
  const float* x  = (const float*)d_in[0];
  const float* wq = (const float*)d_in[1];
  const float* wk = (const float*)d_in[2];
  const float* wv = (const float*)d_in[3];
  float* out = (float*)d_out;

  char* ws = (char*)d_ws;
  // Aliased layout (peak 142 MiB):
  const size_t MB = 1024 * 1024;
  bf16*   xhi = (bf16*)(ws);                         // [0,16M)
  bf16*   xlo = (bf16*)(ws + 16 * MB);               // [16M,32M)
  float2* fkv = (float2*)(ws);                       // [0,32.07M) -- after GEMM
  float2* gtw = (float2*)(ws + 33 * MB);             // [33M,+6KB) twiddles
  bf16*   whi = (bf16*)(ws + 34 * MB);               // [34M,40M)
  bf16*   wlo = (bf16*)(ws + 40 * MB);               // [40M,46M)
  float*  qkv = (float*)(ws + 46 * MB);              // [46M,142M); rows carry Fqh later
  (void)ws_size; (void)in_sizes; (void)n_in; (void)out_size;

  tw_init_k<<<3, 256, 0, stream>>>(gtw);
  prep_x_k<<<BS * DD / 1024, 256, 0, stream>>>(x, xhi, xlo);
  prep_w_k<<<N3 * DD / 1024, 256, 0, stream>>>(wq, wk, wv, whi, wlo);
  gemm_split_k<<<(BS / 128) * (N3 / 128), 256, 0, stream>>>(xhi, xlo, whi, wlo, qkv);
  fwd_fft_k<<<BS, 256, 0, stream>>>(qkv, fkv, gtw);   // fkv overwrites xhi/xlo (dead)
  scan_s_k<<<BB * NBIN, 256, 0, stream>>>(fkv);
  inv_fft_k<<<BS, 256, 0, stream>>>(fkv, qkv, out, gtw);
}